// Round 1
// baseline (174.254 us; speedup 1.0000x reference)
//
#include <hip/hip_runtime.h>

// Problem constants
#define N 160              // input dim
#define K 9                // filter size
#define M 152              // output dim per axis (N - K + 1)
#define S1_CH (N*N*M)      // 3,891,200   stage-1 per-channel elems  [d][h][x]
#define S2_CH (N*M*M)      // 3,696,640   stage-2 per-channel elems  [d][y][x]
#define S3_TOT (M*M*M)     // 3,511,808   output voxels
#define NB3 (S3_TOT/256)   // 13,718 blocks in z-pass
#define INV_WIN (1.0f/729.0f)

// ---------------- Stage 1: moments + x-direction 9-tap box sum ----------------
__global__ __launch_bounds__(256) void lncc_xpass(
    const float* __restrict__ I, const float* __restrict__ J,
    float* __restrict__ S)
{
    int n = blockIdx.x * 256 + threadIdx.x;
    if (n >= S1_CH) return;
    int d   = n / (N * M);
    int rem = n - d * (N * M);
    int h   = rem / M;
    int x   = rem - h * M;
    int base = (d * N + h) * N + x;

    float sI = 0.f, sJ = 0.f, sII = 0.f, sJJ = 0.f, sIJ = 0.f;
#pragma unroll
    for (int k = 0; k < K; ++k) {
        float iv = I[base + k];
        float jv = J[base + k];
        sI += iv;
        sJ += jv;
        sII = fmaf(iv, iv, sII);
        sJJ = fmaf(jv, jv, sJJ);
        sIJ = fmaf(iv, jv, sIJ);
    }
    S[n]            = sI;
    S[S1_CH   + n]  = sJ;
    S[2*S1_CH + n]  = sII;
    S[3*S1_CH + n]  = sJJ;
    S[4*S1_CH + n]  = sIJ;
}

// ---------------- Stage 2: y-direction 9-tap box sum ----------------
__global__ __launch_bounds__(256) void lncc_ypass(
    const float* __restrict__ S, float* __restrict__ T)
{
    int n = blockIdx.x * 256 + threadIdx.x;
    if (n >= S2_CH) return;
    int d   = n / (M * M);
    int rem = n - d * (M * M);
    int y   = rem / M;
    int x   = rem - y * M;
    int base = (d * N + y) * M + x;   // into [d][h][x], h = y..y+8

    float a0 = 0.f, a1 = 0.f, a2 = 0.f, a3 = 0.f, a4 = 0.f;
#pragma unroll
    for (int k = 0; k < K; ++k) {
        int idx = base + k * M;
        a0 += S[idx];
        a1 += S[S1_CH   + idx];
        a2 += S[2*S1_CH + idx];
        a3 += S[3*S1_CH + idx];
        a4 += S[4*S1_CH + idx];
    }
    T[n]            = a0;
    T[S2_CH   + n]  = a1;
    T[2*S2_CH + n]  = a2;
    T[3*S2_CH + n]  = a3;
    T[4*S2_CH + n]  = a4;
}

// ---------------- Stage 3: z-direction 9-tap sum + cc + block reduction ----------------
__global__ __launch_bounds__(256) void lncc_zpass(
    const float* __restrict__ T, float* __restrict__ partial)
{
    int n = blockIdx.x * 256 + threadIdx.x;
    float cc = 0.f;
    if (n < S3_TOT) {
        int z   = n / (M * M);
        int rem = n - z * (M * M);     // y*M + x
        int base = z * (M * M) + rem;  // plane stride = M*M

        float s0 = 0.f, s1 = 0.f, s2 = 0.f, s3 = 0.f, s4 = 0.f;
#pragma unroll
        for (int k = 0; k < K; ++k) {
            int idx = base + k * (M * M);
            s0 += T[idx];
            s1 += T[S2_CH   + idx];
            s2 += T[2*S2_CH + idx];
            s3 += T[3*S2_CH + idx];
            s4 += T[4*S2_CH + idx];
        }
        // cross = IJ - I_sum*J_sum/729 ; var = sq - sum^2/729 (algebraically equal to ref)
        float cross = fmaf(-s0 * s1, INV_WIN, s4);
        float iv    = fmaf(-s0 * s0, INV_WIN, s2);
        float jv    = fmaf(-s1 * s1, INV_WIN, s3);
        cc = (cross * cross) / (iv * jv + 1e-6f);
    }

    // wave (64-lane) reduction, then cross-wave via LDS
    for (int off = 32; off > 0; off >>= 1)
        cc += __shfl_down(cc, off, 64);
    __shared__ float red[4];
    int lane = threadIdx.x & 63;
    int wid  = threadIdx.x >> 6;
    if (lane == 0) red[wid] = cc;
    __syncthreads();
    if (threadIdx.x == 0)
        partial[blockIdx.x] = red[0] + red[1] + red[2] + red[3];
}

// ---------------- Stage 4: final reduction (deterministic, double accum) ----------------
__global__ __launch_bounds__(256) void lncc_final(
    const float* __restrict__ partial, float* __restrict__ out)
{
    double s = 0.0;
    for (int i = threadIdx.x; i < NB3; i += 256)
        s += (double)partial[i];
    for (int off = 32; off > 0; off >>= 1)
        s += __shfl_down(s, off, 64);
    __shared__ double red[4];
    int lane = threadIdx.x & 63;
    int wid  = threadIdx.x >> 6;
    if (lane == 0) red[wid] = s;
    __syncthreads();
    if (threadIdx.x == 0) {
        double tot = red[0] + red[1] + red[2] + red[3];
        out[0] = (float)(1.0 - tot / (double)S3_TOT);
    }
}

extern "C" void kernel_launch(void* const* d_in, const int* in_sizes, int n_in,
                              void* d_out, int out_size, void* d_ws, size_t ws_size,
                              hipStream_t stream) {
    const float* I = (const float*)d_in[0];
    const float* J = (const float*)d_in[1];
    // d_in[2] is the all-ones 9x9x9 filter: folded into the box-sum algebra.

    float* S       = (float*)d_ws;                       // 5 * S1_CH floats
    float* T       = S + 5 * (size_t)S1_CH;              // 5 * S2_CH floats
    float* partial = T + 5 * (size_t)S2_CH;              // NB3 floats
    float* out     = (float*)d_out;

    lncc_xpass<<<S1_CH / 256, 256, 0, stream>>>(I, J, S);
    lncc_ypass<<<S2_CH / 256, 256, 0, stream>>>(S, T);
    lncc_zpass<<<NB3,         256, 0, stream>>>(T, partial);
    lncc_final<<<1,           256, 0, stream>>>(partial, (float*)d_out);
    (void)in_sizes; (void)n_in; (void)out_size; (void)ws_size; (void)out;
}

// Round 2
// 100.022 us; speedup vs baseline: 1.7422x; 1.7422x over previous
//
#include <hip/hip_runtime.h>

// Problem constants
#define N 160              // input dim
#define K 9                // filter size
#define M 152              // output dim per axis (N - K + 1)
#define S1_CH (N*N*M)      // 3,891,200  stage-1 per-channel elems [d][h][xq]
#define S2_CH (N*M*M)      // 3,696,640  stage-2 per-channel elems [d][y][x]
#define S3_TOT ((size_t)M*M*M)
#define INV_WIN (1.0f/729.0f)

// ---- x-pass geometry: each thread emits 4 consecutive x outputs ----
#define QX (M/4)                   // 38 quads per row
#define XP_THREADS (N*N*QX)        // 972,800
#define XP_BLOCKS (XP_THREADS/256) // 3800 (exact)

// ---- y-pass geometry: column walk, 4 y-chunks of 38 ----
#define YCOLS (N*M)                // 24,320 (d,x) columns
#define YP_CBLK (YCOLS/256)        // 95 (exact)
#define YCHUNK 38
#define YP_BLOCKS (YP_CBLK*4)      // 380

// ---- z-pass geometry: column walk, 4 z-chunks of 38 ----
#define ZCOLS (M*M)                // 23,104 (y,x) columns
#define ZP_CBLK ((ZCOLS+255)/256)  // 91
#define ZCHUNK 38
#define ZP_BLOCKS (ZP_CBLK*4)      // 364

// ============ Stage 1: moments + x-direction 9-tap sum (4 outputs/thread) ============
__global__ __launch_bounds__(256) void lncc_xpass(
    const float* __restrict__ I, const float* __restrict__ J,
    float* __restrict__ S)
{
    int n = blockIdx.x * 256 + threadIdx.x;     // < XP_THREADS
    int r = n / QX;                             // row index: d*160 + h
    int q = n - r * QX;
    int x0 = q * 4;
    const float* ip = I + (size_t)r * N + x0;   // reads [x0 .. x0+11], 16B-aligned
    const float* jp = J + (size_t)r * N + x0;

    float iv[12], jv[12];
    const float4 i4a = *(const float4*)(ip);
    const float4 i4b = *(const float4*)(ip + 4);
    const float4 i4c = *(const float4*)(ip + 8);
    const float4 j4a = *(const float4*)(jp);
    const float4 j4b = *(const float4*)(jp + 4);
    const float4 j4c = *(const float4*)(jp + 8);
    iv[0]=i4a.x; iv[1]=i4a.y; iv[2]=i4a.z; iv[3]=i4a.w;
    iv[4]=i4b.x; iv[5]=i4b.y; iv[6]=i4b.z; iv[7]=i4b.w;
    iv[8]=i4c.x; iv[9]=i4c.y; iv[10]=i4c.z; iv[11]=i4c.w;
    jv[0]=j4a.x; jv[1]=j4a.y; jv[2]=j4a.z; jv[3]=j4a.w;
    jv[4]=j4b.x; jv[5]=j4b.y; jv[6]=j4b.z; jv[7]=j4b.w;
    jv[8]=j4c.x; jv[9]=j4c.y; jv[10]=j4c.z; jv[11]=j4c.w;

    size_t obase = (size_t)r * M + x0;
#pragma unroll
    for (int c = 0; c < 5; ++c) {
        float m[12];
#pragma unroll
        for (int k = 0; k < 12; ++k) {
            float a = iv[k], b = jv[k];
            m[k] = (c == 0) ? a
                 : (c == 1) ? b
                 : (c == 2) ? a * a
                 : (c == 3) ? b * b
                 :            a * b;
        }
        float s0 = 0.f;
#pragma unroll
        for (int k = 0; k < 9; ++k) s0 += m[k];
        float s1 = s0 - m[0] + m[9];
        float s2 = s1 - m[1] + m[10];
        float s3 = s2 - m[2] + m[11];
        float4 o; o.x = s0; o.y = s1; o.z = s2; o.w = s3;
        *(float4*)(S + (size_t)c * S1_CH + obase) = o;
    }
}

// ============ Stage 2: y-direction sliding-window walk ============
__global__ __launch_bounds__(256) void lncc_ypass(
    const float* __restrict__ S, float* __restrict__ T)
{
    int chunk = blockIdx.x / YP_CBLK;
    int col   = (blockIdx.x % YP_CBLK) * 256 + threadIdx.x;   // < YCOLS (exact)
    int d = col / M;
    int x = col - d * M;
    int y0 = chunk * YCHUNK;

    float h[9][5];
    float s[5] = {0.f, 0.f, 0.f, 0.f, 0.f};
#pragma unroll
    for (int k = 0; k < 9; ++k) {
        size_t a = ((size_t)d * N + (y0 + k)) * M + x;
#pragma unroll
        for (int c = 0; c < 5; ++c) {
            float v = S[(size_t)c * S1_CH + a];
            h[k][c] = v; s[c] += v;
        }
    }
    size_t o0 = ((size_t)d * M + y0) * M + x;
#pragma unroll
    for (int c = 0; c < 5; ++c) T[(size_t)c * S2_CH + o0] = s[c];

#pragma unroll
    for (int t = 1; t < YCHUNK; ++t) {
        size_t a = ((size_t)d * N + (y0 + 8 + t)) * M + x;
        size_t o = ((size_t)d * M + (y0 + t)) * M + x;
        int p = (t - 1) % 9;
#pragma unroll
        for (int c = 0; c < 5; ++c) {
            float v = S[(size_t)c * S1_CH + a];
            s[c] += v - h[p][c];
            h[p][c] = v;
            T[(size_t)c * S2_CH + o] = s[c];
        }
    }
}

// ============ Stage 3: z-direction sliding walk + cc + block reduction ============
__device__ __forceinline__ float cc_of(const float s[5]) {
    float cross = fmaf(-s[0] * s[1], INV_WIN, s[4]);
    float iv    = fmaf(-s[0] * s[0], INV_WIN, s[2]);
    float jv    = fmaf(-s[1] * s[1], INV_WIN, s[3]);
    return (cross * cross) / (iv * jv + 1e-6f);
}

__global__ __launch_bounds__(256) void lncc_zpass(
    const float* __restrict__ T, float* __restrict__ partial)
{
    int chunk = blockIdx.x / ZP_CBLK;
    int col   = (blockIdx.x % ZP_CBLK) * 256 + threadIdx.x;
    int z0 = chunk * ZCHUNK;
    float cc = 0.f;

    if (col < ZCOLS) {
        float h[9][5];
        float s[5] = {0.f, 0.f, 0.f, 0.f, 0.f};
#pragma unroll
        for (int k = 0; k < 9; ++k) {
            size_t a = (size_t)(z0 + k) * ZCOLS + col;
#pragma unroll
            for (int c = 0; c < 5; ++c) {
                float v = T[(size_t)c * S2_CH + a];
                h[k][c] = v; s[c] += v;
            }
        }
        cc += cc_of(s);
#pragma unroll
        for (int t = 1; t < ZCHUNK; ++t) {
            size_t a = (size_t)(z0 + 8 + t) * ZCOLS + col;
            int p = (t - 1) % 9;
#pragma unroll
            for (int c = 0; c < 5; ++c) {
                float v = T[(size_t)c * S2_CH + a];
                s[c] += v - h[p][c];
                h[p][c] = v;
            }
            cc += cc_of(s);
        }
    }

    // 64-lane wave reduction, then cross-wave via LDS
    for (int off = 32; off > 0; off >>= 1)
        cc += __shfl_down(cc, off, 64);
    __shared__ float red[4];
    int lane = threadIdx.x & 63;
    int wid  = threadIdx.x >> 6;
    if (lane == 0) red[wid] = cc;
    __syncthreads();
    if (threadIdx.x == 0)
        partial[blockIdx.x] = red[0] + red[1] + red[2] + red[3];
}

// ============ Stage 4: final deterministic reduction ============
__global__ __launch_bounds__(256) void lncc_final(
    const float* __restrict__ partial, float* __restrict__ out)
{
    double s = 0.0;
    for (int i = threadIdx.x; i < ZP_BLOCKS; i += 256)
        s += (double)partial[i];
    for (int off = 32; off > 0; off >>= 1)
        s += __shfl_down(s, off, 64);
    __shared__ double red[4];
    int lane = threadIdx.x & 63;
    int wid  = threadIdx.x >> 6;
    if (lane == 0) red[wid] = s;
    __syncthreads();
    if (threadIdx.x == 0) {
        double tot = red[0] + red[1] + red[2] + red[3];
        out[0] = (float)(1.0 - tot / (double)S3_TOT);
    }
}

extern "C" void kernel_launch(void* const* d_in, const int* in_sizes, int n_in,
                              void* d_out, int out_size, void* d_ws, size_t ws_size,
                              hipStream_t stream) {
    const float* I = (const float*)d_in[0];
    const float* J = (const float*)d_in[1];
    // d_in[2]: all-ones 9x9x9 filter, folded into box-sum algebra.

    float* S       = (float*)d_ws;                 // 5 * S1_CH floats
    float* T       = S + 5 * (size_t)S1_CH;        // 5 * S2_CH floats
    float* partial = T + 5 * (size_t)S2_CH;        // ZP_BLOCKS floats

    lncc_xpass<<<XP_BLOCKS, 256, 0, stream>>>(I, J, S);
    lncc_ypass<<<YP_BLOCKS, 256, 0, stream>>>(S, T);
    lncc_zpass<<<ZP_BLOCKS, 256, 0, stream>>>(T, partial);
    lncc_final<<<1,         256, 0, stream>>>(partial, (float*)d_out);
    (void)in_sizes; (void)n_in; (void)out_size; (void)ws_size;
}

// Round 3
// 74.647 us; speedup vs baseline: 2.3344x; 1.3399x over previous
//
#include <hip/hip_runtime.h>

// Problem constants
#define N 160              // input dim
#define K 9                // filter size
#define M 152              // output dim per axis (N - K + 1)
#define S1_CH (N*N*M)      // 3,891,200  stage-1 per-channel elems [d][h][x_out]
#define S2_CH (N*M*M)      // 3,696,640  stage-2 per-channel elems [d][y][x]
#define S3_TOT ((size_t)M*M*M)
#define INV_WIN (1.0f/729.0f)

// ---- x-pass geometry: each thread emits 4 consecutive x outputs ----
#define QX (M/4)                   // 38 quads per row
#define XP_THREADS (N*N*QX)        // 972,800
#define XP_BLOCKS (XP_THREADS/256) // 3800 (exact)

// ---- y-pass geometry: channel-split column walk, 4 y-chunks of 38 ----
#define YCOLS (N*M)                // 24,320 (d,x) columns
#define YP_CBLK (YCOLS/256)        // 95 (exact)
#define YCHUNK 38
#define YP_BLOCKS (YP_CBLK*5*4)    // 1900

// ---- z-pass geometry: column walk, 19 z-chunks of 8 ----
#define ZCOLS (M*M)                // 23,104 (y,x) columns
#define ZP_CBLK ((ZCOLS+255)/256)  // 91
#define ZCHUNK 8
#define ZNCH 19
#define ZP_BLOCKS (ZP_CBLK*ZNCH)   // 1729

// ============ Stage 1: moments + x-direction 9-tap sum (4 outputs/thread) ============
__global__ __launch_bounds__(256) void lncc_xpass(
    const float* __restrict__ I, const float* __restrict__ J,
    float* __restrict__ S)
{
    int n = blockIdx.x * 256 + threadIdx.x;     // < XP_THREADS
    int r = n / QX;                             // row index: d*160 + h
    int q = n - r * QX;
    int x0 = q * 4;
    const float* ip = I + (size_t)r * N + x0;   // reads [x0 .. x0+11], 16B-aligned
    const float* jp = J + (size_t)r * N + x0;

    float iv[12], jv[12];
    const float4 i4a = *(const float4*)(ip);
    const float4 i4b = *(const float4*)(ip + 4);
    const float4 i4c = *(const float4*)(ip + 8);
    const float4 j4a = *(const float4*)(jp);
    const float4 j4b = *(const float4*)(jp + 4);
    const float4 j4c = *(const float4*)(jp + 8);
    iv[0]=i4a.x; iv[1]=i4a.y; iv[2]=i4a.z; iv[3]=i4a.w;
    iv[4]=i4b.x; iv[5]=i4b.y; iv[6]=i4b.z; iv[7]=i4b.w;
    iv[8]=i4c.x; iv[9]=i4c.y; iv[10]=i4c.z; iv[11]=i4c.w;
    jv[0]=j4a.x; jv[1]=j4a.y; jv[2]=j4a.z; jv[3]=j4a.w;
    jv[4]=j4b.x; jv[5]=j4b.y; jv[6]=j4b.z; jv[7]=j4b.w;
    jv[8]=j4c.x; jv[9]=j4c.y; jv[10]=j4c.z; jv[11]=j4c.w;

    size_t obase = (size_t)r * M + x0;
#pragma unroll
    for (int c = 0; c < 5; ++c) {
        float m[12];
#pragma unroll
        for (int k = 0; k < 12; ++k) {
            float a = iv[k], b = jv[k];
            m[k] = (c == 0) ? a
                 : (c == 1) ? b
                 : (c == 2) ? a * a
                 : (c == 3) ? b * b
                 :            a * b;
        }
        float s0 = 0.f;
#pragma unroll
        for (int k = 0; k < 9; ++k) s0 += m[k];
        float s1 = s0 - m[0] + m[9];
        float s2 = s1 - m[1] + m[10];
        float s3 = s2 - m[2] + m[11];
        float4 o; o.x = s0; o.y = s1; o.z = s2; o.w = s3;
        *(float4*)(S + (size_t)c * S1_CH + obase) = o;
    }
}

// ============ Stage 2: y-direction sliding walk, one channel per thread ============
__global__ __launch_bounds__(256) void lncc_ypass(
    const float* __restrict__ S, float* __restrict__ T)
{
    int b      = blockIdx.x;
    int chunk  = b / (5 * YP_CBLK);
    int rem    = b - chunk * (5 * YP_CBLK);
    int c      = rem / YP_CBLK;
    int colblk = rem - c * YP_CBLK;
    int col    = colblk * 256 + threadIdx.x;    // < YCOLS exact
    int d = col / M;
    int x = col - d * M;
    int y0 = chunk * YCHUNK;

    const float* Sc = S + (size_t)c * S1_CH;
    float*       Tc = T + (size_t)c * S2_CH;

    float h[9];
    float s = 0.f;
#pragma unroll
    for (int k = 0; k < 9; ++k) {
        float v = Sc[((size_t)d * N + (y0 + k)) * M + x];
        h[k] = v; s += v;
    }
    Tc[((size_t)d * M + y0) * M + x] = s;

#pragma unroll
    for (int t = 1; t < YCHUNK; ++t) {
        float v = Sc[((size_t)d * N + (y0 + 8 + t)) * M + x];
        int p = (t - 1) % 9;
        s += v - h[p];
        h[p] = v;
        Tc[((size_t)d * M + (y0 + t)) * M + x] = s;
    }
}

// ============ Stage 3: z-direction sliding walk + cc + block reduction ============
__device__ __forceinline__ float cc_of(const float s[5]) {
    float cross = fmaf(-s[0] * s[1], INV_WIN, s[4]);
    float iv    = fmaf(-s[0] * s[0], INV_WIN, s[2]);
    float jv    = fmaf(-s[1] * s[1], INV_WIN, s[3]);
    return (cross * cross) / (iv * jv + 1e-6f);
}

__global__ __launch_bounds__(256) void lncc_zpass(
    const float* __restrict__ T, float* __restrict__ partial)
{
    // chunk innermost: consecutive blocks share halo planes in L2
    int colblk = blockIdx.x / ZNCH;
    int chunk  = blockIdx.x - colblk * ZNCH;
    int col    = colblk * 256 + threadIdx.x;
    int z0 = chunk * ZCHUNK;
    float cc = 0.f;

    if (col < ZCOLS) {
        float h[9][5];
        float s[5] = {0.f, 0.f, 0.f, 0.f, 0.f};
#pragma unroll
        for (int k = 0; k < 9; ++k) {
            size_t a = (size_t)(z0 + k) * ZCOLS + col;
#pragma unroll
            for (int c = 0; c < 5; ++c) {
                float v = T[(size_t)c * S2_CH + a];
                h[k][c] = v; s[c] += v;
            }
        }
        cc += cc_of(s);
#pragma unroll
        for (int t = 1; t < ZCHUNK; ++t) {
            size_t a = (size_t)(z0 + 8 + t) * ZCOLS + col;
            int p = (t - 1) % 9;
#pragma unroll
            for (int c = 0; c < 5; ++c) {
                float v = T[(size_t)c * S2_CH + a];
                s[c] += v - h[p][c];
                h[p][c] = v;
            }
            cc += cc_of(s);
        }
    }

    // 64-lane wave reduction, then cross-wave via LDS
    for (int off = 32; off > 0; off >>= 1)
        cc += __shfl_down(cc, off, 64);
    __shared__ float red[4];
    int lane = threadIdx.x & 63;
    int wid  = threadIdx.x >> 6;
    if (lane == 0) red[wid] = cc;
    __syncthreads();
    if (threadIdx.x == 0)
        partial[blockIdx.x] = red[0] + red[1] + red[2] + red[3];
}

// ============ Stage 4: final deterministic reduction ============
__global__ __launch_bounds__(256) void lncc_final(
    const float* __restrict__ partial, float* __restrict__ out)
{
    double s = 0.0;
    for (int i = threadIdx.x; i < ZP_BLOCKS; i += 256)
        s += (double)partial[i];
    for (int off = 32; off > 0; off >>= 1)
        s += __shfl_down(s, off, 64);
    __shared__ double red[4];
    int lane = threadIdx.x & 63;
    int wid  = threadIdx.x >> 6;
    if (lane == 0) red[wid] = s;
    __syncthreads();
    if (threadIdx.x == 0) {
        double tot = red[0] + red[1] + red[2] + red[3];
        out[0] = (float)(1.0 - tot / (double)S3_TOT);
    }
}

extern "C" void kernel_launch(void* const* d_in, const int* in_sizes, int n_in,
                              void* d_out, int out_size, void* d_ws, size_t ws_size,
                              hipStream_t stream) {
    const float* I = (const float*)d_in[0];
    const float* J = (const float*)d_in[1];
    // d_in[2]: all-ones 9x9x9 filter, folded into box-sum algebra.

    float* S       = (float*)d_ws;                 // 5 * S1_CH floats
    float* T       = S + 5 * (size_t)S1_CH;        // 5 * S2_CH floats
    float* partial = T + 5 * (size_t)S2_CH;        // ZP_BLOCKS floats

    lncc_xpass<<<XP_BLOCKS, 256, 0, stream>>>(I, J, S);
    lncc_ypass<<<YP_BLOCKS, 256, 0, stream>>>(S, T);
    lncc_zpass<<<ZP_BLOCKS, 256, 0, stream>>>(T, partial);
    lncc_final<<<1,         256, 0, stream>>>(partial, (float*)d_out);
    (void)in_sizes; (void)n_in; (void)out_size; (void)ws_size;
}

// Round 4
// 66.889 us; speedup vs baseline: 2.6051x; 1.1160x over previous
//
#include <hip/hip_runtime.h>

// ---- problem geometry ----
#define NN 160             // input dim
#define MM 152             // output dim (160-9+1)
#define TO 16              // output tile edge (y and x)
#define TI 24              // input tile edge = TO+8
#define TIP 25             // padded LDS row stride (odd -> conflict-free)
#define ZC 19              // z-outputs per block (152 = 8*19)
#define PL 27              // input planes per block = ZC+8
#define NTX 10             // tiles per axis (10*16=160 covers 152)
#define NTILE 100
#define NZ 8
#define NBLK (NTILE*NZ)    // 800
#define INV_WIN (1.0f/729.0f)

__device__ __forceinline__ float meval(int c, float a, float b) {
    // moment channel: 0:I 1:J 2:I^2 3:J^2 4:IJ  (select chain, no divergence)
    float m = a;
    m = (c == 1) ? b     : m;
    m = (c == 2) ? a * a : m;
    m = (c == 3) ? b * b : m;
    m = (c == 4) ? a * b : m;
    return m;
}

__device__ __forceinline__ float cc_of(const float* s) {
    float cross = fmaf(-s[0] * s[1], INV_WIN, s[4]);
    float iv    = fmaf(-s[0] * s[0], INV_WIN, s[2]);
    float jv    = fmaf(-s[1] * s[1], INV_WIN, s[3]);
    return (cross * cross) / (iv * jv + 1e-6f);
}

__global__ __launch_bounds__(256, 4) void lncc_fused(
    const float* __restrict__ I, const float* __restrict__ J,
    float* __restrict__ partial)
{
    __shared__ float Ild[TI][TIP];     // raw input plane tile
    __shared__ float Jld[TI][TIP];
    __shared__ float xs[5][TI][17];    // x-box-sums  [ch][row][x_out]
    __shared__ float ys[5][TO][17];    // xy-box-sums [ch][y_out][x_out]
    __shared__ float red[4];

    const int tid  = threadIdx.x;
    const int bid  = blockIdx.x;
    const int tile = bid % NTILE;      // fast index: tiles of one z-chunk share planes in L2/L3
    const int zc   = bid / NTILE;
    const int x0 = (tile % NTX) * TO;
    const int y0 = (tile / NTX) * TO;
    const int z0 = zc * ZC;

    const int yl = tid >> 4, xl = tid & 15;
    const bool valid = (x0 + xl < MM) && (y0 + yl < MM);

    // global-load mapping: 144 float4s per channel per plane (24 rows x 6 quads)
    const int lrow = tid / 6;
    const int lq   = tid - 6 * lrow;
    const int gy   = min(y0 + lrow, NN - 1);       // clamp: only feeds invalid outputs
    const int gx   = min(x0 + lq * 4, NN - 4);
    const size_t pbase = (size_t)gy * NN + gx;

    float4 pI, pJ;                                  // prefetch registers
    if (tid < 144) {
        size_t a = (size_t)z0 * (NN * NN) + pbase;
        pI = *(const float4*)(I + a);
        pJ = *(const float4*)(J + a);
    }

    float ring[9][5];                               // z-window history (static idx only)
    float sz[5] = {0.f, 0.f, 0.f, 0.f, 0.f};
    float cc_acc = 0.f;

    for (int pb = 0; pb < PL; pb += 9) {
#pragma unroll
        for (int pi = 0; pi < 9; ++pi) {
            const int p = pb + pi;                  // plane index 0..26 (pb runtime, pi static)
            if (p >= PL) continue;                  // pb=18: pi<=8 -> p<=26, always false; keeps safety

            // ---- W: commit prefetched plane p to LDS ----
            if (tid < 144) {
                Ild[lrow][lq*4+0] = pI.x; Ild[lrow][lq*4+1] = pI.y;
                Ild[lrow][lq*4+2] = pI.z; Ild[lrow][lq*4+3] = pI.w;
                Jld[lrow][lq*4+0] = pJ.x; Jld[lrow][lq*4+1] = pJ.y;
                Jld[lrow][lq*4+2] = pJ.z; Jld[lrow][lq*4+3] = pJ.w;
            }
            // ---- P: prefetch plane p+1 (hides HBM latency under X/Y/Z) ----
            if (p < PL - 1 && tid < 144) {
                size_t a = (size_t)(z0 + p + 1) * (NN * NN) + pbase;
                pI = *(const float4*)(I + a);
                pJ = *(const float4*)(J + a);
            }
            __syncthreads();

            // ---- X: x-direction 9-tap sums. items = (row 0..23, half, ch) = 240 ----
            if (tid < 240) {
                const int c   = tid % 5;
                const int rh  = tid / 5;            // 0..47
                const int row = rh >> 1;
                const int xb  = (rh & 1) * 8;
                const float* Ir = &Ild[row][0];
                const float* Jr = &Jld[row][0];
                float s = 0.f;
#pragma unroll
                for (int k = 0; k < 9; ++k) s += meval(c, Ir[xb + k], Jr[xb + k]);
                xs[c][row][xb] = s;
#pragma unroll
                for (int t = 1; t < 8; ++t) {
                    s += meval(c, Ir[xb + t + 8], Jr[xb + t + 8])
                       - meval(c, Ir[xb + t - 1], Jr[xb + t - 1]);
                    xs[c][row][xb + t] = s;
                }
            }
            __syncthreads();

            // ---- Y: y-direction 9-tap sums. items = (ch, x, yhalf) = 160 ----
            if (tid < 160) {
                const int c  = tid % 5;
                const int xh = tid / 5;             // 0..31
                const int x  = xh & 15;
                const int yb = (xh >> 4) * 8;
                float s = 0.f;
#pragma unroll
                for (int k = 0; k < 9; ++k) s += xs[c][yb + k][x];
                ys[c][yb][x] = s;
#pragma unroll
                for (int t = 1; t < 8; ++t) {
                    s += xs[c][yb + t + 8][x] - xs[c][yb + t - 1][x];
                    ys[c][yb + t][x] = s;
                }
            }
            __syncthreads();

            // ---- Z: per-column sliding z-window + cc ----
            {
                float v[5];
#pragma unroll
                for (int c = 0; c < 5; ++c) {
                    v[c] = ys[c][yl][xl];
                    sz[c] += v[c];
                    ring[pi][c] = v[c];             // pi static -> registers
                }
                if (p >= 8) {                       // block-uniform branch
                    cc_acc += valid ? cc_of(sz) : 0.f;
                    const int q = (pi + 1) % 9;     // static
#pragma unroll
                    for (int c = 0; c < 5; ++c) sz[c] -= ring[q][c];
                }
            }
        }
    }

    // ---- block reduction (deterministic) ----
    for (int off = 32; off > 0; off >>= 1)
        cc_acc += __shfl_down(cc_acc, off, 64);
    const int lane = tid & 63, wid = tid >> 6;
    if (lane == 0) red[wid] = cc_acc;
    __syncthreads();
    if (tid == 0) partial[bid] = red[0] + red[1] + red[2] + red[3];
}

// ---- final deterministic reduction over 800 partials ----
__global__ __launch_bounds__(256) void lncc_final(
    const float* __restrict__ partial, float* __restrict__ out)
{
    double s = 0.0;
    for (int i = threadIdx.x; i < NBLK; i += 256)
        s += (double)partial[i];
    for (int off = 32; off > 0; off >>= 1)
        s += __shfl_down(s, off, 64);
    __shared__ double red[4];
    const int lane = threadIdx.x & 63, wid = threadIdx.x >> 6;
    if (lane == 0) red[wid] = s;
    __syncthreads();
    if (threadIdx.x == 0) {
        double tot = red[0] + red[1] + red[2] + red[3];
        out[0] = (float)(1.0 - tot / ((double)MM * MM * MM));
    }
}

extern "C" void kernel_launch(void* const* d_in, const int* in_sizes, int n_in,
                              void* d_out, int out_size, void* d_ws, size_t ws_size,
                              hipStream_t stream) {
    const float* I = (const float*)d_in[0];
    const float* J = (const float*)d_in[1];
    // d_in[2]: all-ones 9x9x9 filter, folded into the box-sum algebra.

    float* partial = (float*)d_ws;                  // NBLK floats

    lncc_fused<<<NBLK, 256, 0, stream>>>(I, J, partial);
    lncc_final<<<1,    256, 0, stream>>>(partial, (float*)d_out);
    (void)in_sizes; (void)n_in; (void)out_size; (void)ws_size;
}

// Round 5
// 50.104 us; speedup vs baseline: 3.4779x; 1.3350x over previous
//
#include <hip/hip_runtime.h>

// ---- problem geometry ----
#define NN 160             // input dim
#define MM 152             // output dim (160-9+1)
#define TO 16              // output tile edge (y and x)
#define TI 24              // input tile edge = TO+8
#define PSTR 28            // Pld row stride (floats): 112B rows, 16B-aligned
#define XSTR 28            // xs row-dim stride (floats), 16B-aligned
#define YSTR 20            // ys y-dim stride (floats), 16B-aligned
#define ZC 19              // z-outputs per block (152 = 8*19)
#define PL (ZC+8)          // 27 input planes per block
#define KMAX (PL+2)        // 29 pipeline iterations - 1
#define NZ 8
#define NTX 10
#define NTILE 100
#define NBLK (NTILE*NZ)    // 800
#define INV_WIN (1.0f/729.0f)

__device__ __forceinline__ float cc_of(const float* s) {
    float cross = fmaf(-s[0] * s[1], INV_WIN, s[4]);
    float iv    = fmaf(-s[0] * s[0], INV_WIN, s[2]);
    float jv    = fmaf(-s[1] * s[1], INV_WIN, s[3]);
    return (cross * cross) / (iv * jv + 1e-6f);
}

__global__ __launch_bounds__(256, 3) void lncc_fused(
    const float* __restrict__ I, const float* __restrict__ J,
    float* __restrict__ partial)
{
    // Pld: 5 product channels of current input plane   (13440 B)
    // xs : x-sums, TRANSPOSED [c][x_out][row], dbuf     (17920 B)
    // ys : xy-sums [c][x_out][y_out], dbuf              (12800 B)
    __shared__ float Pld[5][TI][PSTR];
    __shared__ float xs[2][5][TO][XSTR];
    __shared__ float ys[2][5][TO][YSTR];
    __shared__ float red[4];

    const int tid  = threadIdx.x;
    const int orig = blockIdx.x;
    const int bid  = (orig & 7) * NTILE + (orig >> 3);  // XCD-chunk swizzle (800%8==0)
    const int tile = bid % NTILE;
    const int zc   = bid / NTILE;
    const int x0 = (tile % NTX) * TO;
    const int y0 = (tile / NTX) * TO;
    const int z0 = zc * ZC;

    const int yl = tid >> 4, xl = tid & 15;
    const bool valid = (x0 + xl < MM) && (y0 + yl < MM);

    // loader mapping (tid < 144): one float4-quad per thread, 24 rows x 6 quads
    const int lrow = tid / 6;
    const int lq   = tid - 6 * lrow;
    const int gy   = min(y0 + lrow, NN - 1);     // clamps only feed invalid outputs
    const int gx   = min(x0 + lq * 4, NN - 4);
    const size_t pbase = (size_t)gy * NN + gx;

    // X mapping (tid >= 16): 240 items = (ch, row, half)
    const int eX   = tid - 16;
    const int hX   = eX & 1;
    const int rrX  = eX >> 1;
    const int rowX = rrX % 24;
    const int cX   = rrX / 24;
    const int xbX  = hX * 8;

    // Y mapping (tid >= 96): 160 items = (ch, x, yhalf)
    const int eY  = tid - 96;
    const int cY  = eY >> 5;
    const int xY  = eY & 15;
    const int ybY = ((eY >> 4) & 1) * 8;

    float4 pI, pJ;                                // prefetch registers
    if (tid < 144) {
        size_t a = (size_t)z0 * (NN * NN) + pbase;
        pI = *(const float4*)(I + a);
        pJ = *(const float4*)(J + a);
    }

    float ring[9][5];                             // z-window history (static idx only)
    float sz[5] = {0.f, 0.f, 0.f, 0.f, 0.f};
    float cc_acc = 0.f;

    for (int kb = 0; kb <= KMAX; kb += 9) {
#pragma unroll
        for (int ki = 0; ki < 9; ++ki) {
            const int k = kb + ki;                // pipeline step (block-uniform)
            if (k > KMAX) continue;

            // ================= Group 1: X(k-1) | Y(k-2) | Z(k-3) =================
            if (k >= 1 && k <= PL && tid >= 16) {
                // X: x-direction 9-tap sliding sums from Pld -> xs[(k-1)&1]
                const int b = (k - 1) & 1;
                const float4* P4 = (const float4*)&Pld[cX][rowX][0];
                float4 v0 = P4[hX * 2 + 0];
                float4 v1 = P4[hX * 2 + 1];
                float4 v2 = P4[hX * 2 + 2];
                float4 v3 = P4[hX * 2 + 3];
                float m[16];
                m[0]=v0.x;  m[1]=v0.y;  m[2]=v0.z;  m[3]=v0.w;
                m[4]=v1.x;  m[5]=v1.y;  m[6]=v1.z;  m[7]=v1.w;
                m[8]=v2.x;  m[9]=v2.y;  m[10]=v2.z; m[11]=v2.w;
                m[12]=v3.x; m[13]=v3.y; m[14]=v3.z; m[15]=v3.w;
                float s = m[0]+m[1]+m[2]+m[3]+m[4]+m[5]+m[6]+m[7]+m[8];
                float* W = &xs[b][cX][0][0];
                W[(xbX + 0) * XSTR + rowX] = s;
#pragma unroll
                for (int t = 1; t < 8; ++t) {
                    s += m[t + 8] - m[t - 1];
                    W[(xbX + t) * XSTR + rowX] = s;
                }
            }
            if (k >= 2 && k <= PL + 1 && tid >= 96) {
                // Y: y-direction 9-tap sliding sums from xs[(k-2)&1] -> ys[(k-2)&1]
                const int b = (k - 2) & 1;
                const float4* R4 = (const float4*)&xs[b][cY][xY][0];
                float4 w0 = R4[ybY / 4 + 0];
                float4 w1 = R4[ybY / 4 + 1];
                float4 w2 = R4[ybY / 4 + 2];
                float4 w3 = R4[ybY / 4 + 3];
                float m[16];
                m[0]=w0.x;  m[1]=w0.y;  m[2]=w0.z;  m[3]=w0.w;
                m[4]=w1.x;  m[5]=w1.y;  m[6]=w1.z;  m[7]=w1.w;
                m[8]=w2.x;  m[9]=w2.y;  m[10]=w2.z; m[11]=w2.w;
                m[12]=w3.x; m[13]=w3.y; m[14]=w3.z; m[15]=w3.w;
                float o[8];
                float s = m[0]+m[1]+m[2]+m[3]+m[4]+m[5]+m[6]+m[7]+m[8];
                o[0] = s;
#pragma unroll
                for (int t = 1; t < 8; ++t) {
                    s += m[t + 8] - m[t - 1];
                    o[t] = s;
                }
                float4* Wv = (float4*)&ys[b][cY][xY][ybY];
                float4 oa = {o[0], o[1], o[2], o[3]};
                float4 ob = {o[4], o[5], o[6], o[7]};
                Wv[0] = oa;
                Wv[1] = ob;
            }
            if (k >= 3) {
                // Z: per-column sliding z-window over ys[(k-3)&1] + cc
                const int b = (k - 3) & 1;
                const int slot  = (ki + 6) % 9;   // (k-3)%9, compile-time per unrolled copy
                const int slot2 = (ki + 7) % 9;   // (k-3-8)%9
                float v[5];
#pragma unroll
                for (int c = 0; c < 5; ++c) {
                    v[c] = ys[b][c][xl][yl];
                    sz[c] += v[c];
                    ring[slot][c] = v[c];
                }
                if (k >= 11) {                    // pz = k-3 >= 8: emit output
                    cc_acc += valid ? cc_of(sz) : 0.f;
#pragma unroll
                    for (int c = 0; c < 5; ++c) sz[c] -= ring[slot2][c];
                }
            }
            __syncthreads();

            // ================= Group 2: commit(k) + prefetch(k+1) =================
            if (k <= PL - 1 && tid < 144) {
                float4 a = pI, bq = pJ;
                *(float4*)&Pld[0][lrow][lq * 4] = a;
                *(float4*)&Pld[1][lrow][lq * 4] = bq;
                float4 ii = {a.x*a.x,  a.y*a.y,  a.z*a.z,  a.w*a.w};
                float4 jj = {bq.x*bq.x, bq.y*bq.y, bq.z*bq.z, bq.w*bq.w};
                float4 ij = {a.x*bq.x, a.y*bq.y, a.z*bq.z, a.w*bq.w};
                *(float4*)&Pld[2][lrow][lq * 4] = ii;
                *(float4*)&Pld[3][lrow][lq * 4] = jj;
                *(float4*)&Pld[4][lrow][lq * 4] = ij;
                if (k <= PL - 2) {
                    size_t adr = (size_t)(z0 + k + 1) * (NN * NN) + pbase;
                    pI = *(const float4*)(I + adr);
                    pJ = *(const float4*)(J + adr);
                }
            }
            __syncthreads();
        }
    }

    // ---- block reduction (deterministic) ----
    for (int off = 32; off > 0; off >>= 1)
        cc_acc += __shfl_down(cc_acc, off, 64);
    if ((tid & 63) == 0) red[tid >> 6] = cc_acc;
    __syncthreads();
    if (tid == 0) partial[orig] = red[0] + red[1] + red[2] + red[3];
}

// ---- final deterministic reduction over 800 partials ----
__global__ __launch_bounds__(256) void lncc_final(
    const float* __restrict__ partial, float* __restrict__ out)
{
    double s = 0.0;
    for (int i = threadIdx.x; i < NBLK; i += 256)
        s += (double)partial[i];
    for (int off = 32; off > 0; off >>= 1)
        s += __shfl_down(s, off, 64);
    __shared__ double red[4];
    const int lane = threadIdx.x & 63, wid = threadIdx.x >> 6;
    if (lane == 0) red[wid] = s;
    __syncthreads();
    if (threadIdx.x == 0) {
        double tot = red[0] + red[1] + red[2] + red[3];
        out[0] = (float)(1.0 - tot / ((double)MM * MM * MM));
    }
}

extern "C" void kernel_launch(void* const* d_in, const int* in_sizes, int n_in,
                              void* d_out, int out_size, void* d_ws, size_t ws_size,
                              hipStream_t stream) {
    const float* I = (const float*)d_in[0];
    const float* J = (const float*)d_in[1];
    // d_in[2]: all-ones 9x9x9 filter, folded into the box-sum algebra.

    float* partial = (float*)d_ws;                 // NBLK floats

    lncc_fused<<<NBLK, 256, 0, stream>>>(I, J, partial);
    lncc_final<<<1,    256, 0, stream>>>(partial, (float*)d_out);
    (void)in_sizes; (void)n_in; (void)out_size; (void)ws_size;
}

// Round 6
// 47.624 us; speedup vs baseline: 3.6590x; 1.0521x over previous
//
#include <hip/hip_runtime.h>

// ---- problem geometry ----
#define NN 160             // input dim
#define MM 152             // output dim (160-9+1)
#define TO 16              // output tile edge (y and x)
#define TI 24              // input tile edge = TO+8
#define PSTR 28            // Pld row stride (floats), 16B-aligned
#define PCH  (TI*PSTR+4)   // 676: Pld channel stride; 676%32=4 -> banks spread
#define XROW 28            // xs inner (row) dim stride
#define XCH  (TO*XROW+4)   // 452: xs channel stride; %32=4
#define YROW 20            // ys inner (y) dim stride
#define YCH  (TO*YROW+4)   // 324: ys channel stride; %32=4
#define ZC 19              // z-outputs per block (152 = 8*19)
#define PL (ZC+8)          // 27 input planes per block
#define KMAX (PL+2)        // 29: pipeline steps 0..29
#define NZ 8
#define NTX 10
#define NTILE 100
#define NBLK (NTILE*NZ)    // 800
#define INV_WIN (1.0f/729.0f)

__device__ __forceinline__ float cc_of(const float* s) {
    float cross = fmaf(-s[0] * s[1], INV_WIN, s[4]);
    float iv    = fmaf(-s[0] * s[0], INV_WIN, s[2]);
    float jv    = fmaf(-s[1] * s[1], INV_WIN, s[3]);
    return (cross * cross) / (iv * jv + 1e-6f);
}

__global__ __launch_bounds__(256, 4) void lncc_fused(
    const float* __restrict__ I, const float* __restrict__ J,
    float* __restrict__ partial)
{
    __shared__ float Pld[2 * PCH];        // raw I,J plane tile (5408 B)
    __shared__ float xsb[2][5 * XCH];     // x-sums, transposed [c][x_out][row], dbuf (18080 B)
    __shared__ float ysb[2][5 * YCH];     // xy-sums [c][x_out][y_out], dbuf (12960 B)
    __shared__ float red[4];

    const int tid  = threadIdx.x;
    const int orig = blockIdx.x;
    const int bid  = (orig & 7) * NTILE + (orig >> 3);  // XCD-chunk swizzle (800%8==0)
    const int tile = bid % NTILE;
    const int zc   = bid / NTILE;
    const int x0 = (tile % NTX) * TO;
    const int y0 = (tile / NTX) * TO;
    const int z0 = zc * ZC;

    const int yl = tid >> 4, xl = tid & 15;
    const bool valid = (x0 + xl < MM) && (y0 + yl < MM);

    // loader mapping (tid < 144): 24 rows x 6 quads, one float4 per array
    const int lrow = tid / 6;
    const int lq   = tid - 6 * lrow;
    const int gy   = min(y0 + lrow, NN - 1);   // clamps only feed invalid outputs
    const int gx   = min(x0 + lq * 4, NN - 4);
    const size_t pbase = (size_t)gy * NN + gx;

    // X mapping (tid >= 16): 240 items = (ch, row, half)
    const int eX   = tid - 16;
    const int hX   = eX & 1;
    const int rrX  = eX >> 1;
    const int rowX = rrX % 24;
    const int cX   = rrX / 24;
    const int xbX  = hX * 8;

    // Y mapping (tid >= 96): 160 items = (ch, x, yhalf)
    const int eY  = tid - 96;
    const int cY  = eY >> 5;
    const int xY  = eY & 15;
    const int ybY = ((eY >> 4) & 1) * 8;

    float4 pI, pJ;                             // prefetch registers
    if (tid < 144) {
        size_t a = (size_t)z0 * (NN * NN) + pbase;
        pI = *(const float4*)(I + a);
        pJ = *(const float4*)(J + a);
    }

    float ring[9][5];                          // z-window history (static idx only)
    float sz[5] = {0.f, 0.f, 0.f, 0.f, 0.f};
    float cc_acc = 0.f;

    for (int kb = 0; kb <= KMAX; kb += 9) {
#pragma unroll
        for (int ki = 0; ki < 9; ++ki) {
            const int k = kb + ki;             // pipeline step (block-uniform)
            if (k > KMAX) continue;

            // ============== Group 1: X(k-1) | Y(k-2) ==============
            if (k >= 1 && k <= PL && tid >= 16) {
                // X: read 16-float I,J windows, branchless channel product, slide
                const int b = (k - 1) & 1;
                const float4* Ir = (const float4*)&Pld[rowX * PSTR];
                const float4* Jr = (const float4*)&Pld[PCH + rowX * PSTR];
                float4 i0 = Ir[hX*2+0], i1 = Ir[hX*2+1], i2 = Ir[hX*2+2], i3 = Ir[hX*2+3];
                float4 j0 = Jr[hX*2+0], j1 = Jr[hX*2+1], j2 = Jr[hX*2+2], j3 = Jr[hX*2+3];
                float iv[16], jv[16];
                iv[0]=i0.x; iv[1]=i0.y; iv[2]=i0.z; iv[3]=i0.w;
                iv[4]=i1.x; iv[5]=i1.y; iv[6]=i1.z; iv[7]=i1.w;
                iv[8]=i2.x; iv[9]=i2.y; iv[10]=i2.z; iv[11]=i2.w;
                iv[12]=i3.x; iv[13]=i3.y; iv[14]=i3.z; iv[15]=i3.w;
                jv[0]=j0.x; jv[1]=j0.y; jv[2]=j0.z; jv[3]=j0.w;
                jv[4]=j1.x; jv[5]=j1.y; jv[6]=j1.z; jv[7]=j1.w;
                jv[8]=j2.x; jv[9]=j2.y; jv[10]=j2.z; jv[11]=j2.w;
                jv[12]=j3.x; jv[13]=j3.y; jv[14]=j3.z; jv[15]=j3.w;
                float m[16];
#pragma unroll
                for (int t = 0; t < 16; ++t) {
                    float av = (cX & 1) ? jv[t] : iv[t];           // c:0,2,4->I  1,3->J
                    float bv = (cX < 2) ? 1.0f : ((cX == 2) ? iv[t] : jv[t]);
                    m[t] = av * bv;
                }
                float s = m[0]+m[1]+m[2]+m[3]+m[4]+m[5]+m[6]+m[7]+m[8];
                float* W = &xsb[b][cX * XCH + rowX];
                W[xbX * XROW] = s;
#pragma unroll
                for (int t = 1; t < 8; ++t) {
                    s += m[t + 8] - m[t - 1];
                    W[(xbX + t) * XROW] = s;
                }
            }
            if (k >= 2 && k <= PL + 1 && tid >= 96) {
                // Y: y-direction 9-tap sliding sums from xs -> ys
                const int b = (k - 2) & 1;
                const float4* R4 = (const float4*)&xsb[b][cY * XCH + xY * XROW];
                float4 w0 = R4[ybY/4 + 0];
                float4 w1 = R4[ybY/4 + 1];
                float4 w2 = R4[ybY/4 + 2];
                float4 w3 = R4[ybY/4 + 3];
                float m[16];
                m[0]=w0.x;  m[1]=w0.y;  m[2]=w0.z;  m[3]=w0.w;
                m[4]=w1.x;  m[5]=w1.y;  m[6]=w1.z;  m[7]=w1.w;
                m[8]=w2.x;  m[9]=w2.y;  m[10]=w2.z; m[11]=w2.w;
                m[12]=w3.x; m[13]=w3.y; m[14]=w3.z; m[15]=w3.w;
                float o[8];
                float s = m[0]+m[1]+m[2]+m[3]+m[4]+m[5]+m[6]+m[7]+m[8];
                o[0] = s;
#pragma unroll
                for (int t = 1; t < 8; ++t) {
                    s += m[t + 8] - m[t - 1];
                    o[t] = s;
                }
                float4* Wv = (float4*)&ysb[b][cY * YCH + xY * YROW + ybY];
                float4 oa = {o[0], o[1], o[2], o[3]};
                float4 ob = {o[4], o[5], o[6], o[7]};
                Wv[0] = oa;
                Wv[1] = ob;
            }
            __syncthreads();

            // ============== Group 2: commit(k)+prefetch(k+1) | Z(k-3) ==============
            if (k <= PL - 1 && tid < 144) {
                *(float4*)&Pld[lrow * PSTR + lq * 4]       = pI;
                *(float4*)&Pld[PCH + lrow * PSTR + lq * 4] = pJ;
                if (k <= PL - 2) {
                    size_t adr = (size_t)(z0 + k + 1) * (NN * NN) + pbase;
                    pI = *(const float4*)(I + adr);
                    pJ = *(const float4*)(J + adr);
                }
            }
            if (k >= 3) {
                // Z: per-column sliding z-window over ys[(k-3)&1] + cc
                const int b = (k - 3) & 1;
                const int slot  = (ki + 6) % 9;   // (k-3)%9, static per unrolled copy
                const int slot2 = (ki + 7) % 9;   // (k-3-8)%9
                float v[5];
#pragma unroll
                for (int c = 0; c < 5; ++c) {
                    v[c] = ysb[b][c * YCH + xl * YROW + yl];
                    sz[c] += v[c];
                    ring[slot][c] = v[c];
                }
                if (k >= 11) {                    // pz = k-3 >= 8: emit output
                    cc_acc += valid ? cc_of(sz) : 0.f;
#pragma unroll
                    for (int c = 0; c < 5; ++c) sz[c] -= ring[slot2][c];
                }
            }
            __syncthreads();
        }
    }

    // ---- block reduction (deterministic) ----
    for (int off = 32; off > 0; off >>= 1)
        cc_acc += __shfl_down(cc_acc, off, 64);
    if ((tid & 63) == 0) red[tid >> 6] = cc_acc;
    __syncthreads();
    if (tid == 0) partial[orig] = red[0] + red[1] + red[2] + red[3];
}

// ---- final deterministic reduction over 800 partials ----
__global__ __launch_bounds__(256) void lncc_final(
    const float* __restrict__ partial, float* __restrict__ out)
{
    double s = 0.0;
    for (int i = threadIdx.x; i < NBLK; i += 256)
        s += (double)partial[i];
    for (int off = 32; off > 0; off >>= 1)
        s += __shfl_down(s, off, 64);
    __shared__ double red[4];
    const int lane = threadIdx.x & 63, wid = threadIdx.x >> 6;
    if (lane == 0) red[wid] = s;
    __syncthreads();
    if (threadIdx.x == 0) {
        double tot = red[0] + red[1] + red[2] + red[3];
        out[0] = (float)(1.0 - tot / ((double)MM * MM * MM));
    }
}

extern "C" void kernel_launch(void* const* d_in, const int* in_sizes, int n_in,
                              void* d_out, int out_size, void* d_ws, size_t ws_size,
                              hipStream_t stream) {
    const float* I = (const float*)d_in[0];
    const float* J = (const float*)d_in[1];
    // d_in[2]: all-ones 9x9x9 filter, folded into the box-sum algebra.

    float* partial = (float*)d_ws;             // NBLK floats

    lncc_fused<<<NBLK, 256, 0, stream>>>(I, J, partial);
    lncc_final<<<1,    256, 0, stream>>>(partial, (float*)d_out);
    (void)in_sizes; (void)n_in; (void)out_size; (void)ws_size;
}

// Round 7
// 41.259 us; speedup vs baseline: 4.2234x; 1.1543x over previous
//
#include <hip/hip_runtime.h>

// ---- problem geometry ----
#define NN 160             // input dim
#define MM 152             // output dim (160-9+1)
#define TO 16              // output tile edge (y and x)
#define TI 24              // input tile edge = TO+8
#define PSTR 28            // Pld row stride (floats), 16B-aligned
#define PCH  (TI*PSTR+4)   // 676: Pld channel stride
#define XROW 28            // xs x-dim stride (row dim is inner, contiguous)
#define XCH  (TO*XROW+4)   // 452: xs channel stride
#define YROW 20            // ys x-dim stride (y dim is inner, contiguous)
#define YCH  (TO*YROW+4)   // 324: ys channel stride
#define ZC 19              // z-outputs per block (152 = 8*19)
#define PL (ZC+8)          // 27 input planes per block
#define KMAX (PL+2)        // 29: pipeline steps 0..29
#define NZ 8
#define NTX 10
#define NTILE 100
#define NBLK (NTILE*NZ)    // 800
#define INV_WIN (1.0f/729.0f)

__device__ __forceinline__ float cc_of(const float* s) {
    float cross = fmaf(-s[0] * s[1], INV_WIN, s[4]);
    float iv    = fmaf(-s[0] * s[0], INV_WIN, s[2]);
    float jv    = fmaf(-s[1] * s[1], INV_WIN, s[3]);
    return (cross * cross) / (iv * jv + 1e-6f);
}

__global__ __launch_bounds__(256, 4) void lncc_fused(
    const float* __restrict__ I, const float* __restrict__ J,
    float* __restrict__ partial)
{
    __shared__ float Pld[2 * PCH];        // raw I,J plane tile (5408 B)
    __shared__ float xsb[2][5 * XCH];     // x-sums [c][x][row], dbuf (18080 B)
    __shared__ float ysb[2][5 * YCH];     // xy-sums [c][x][y], dbuf (12960 B)
    __shared__ float red[4];

    const int tid  = threadIdx.x;
    const int orig = blockIdx.x;
    const int bid  = (orig & 7) * NTILE + (orig >> 3);  // XCD-chunk swizzle (800%8==0)
    const int tile = bid % NTILE;
    const int zc   = bid / NTILE;
    const int x0 = (tile % NTX) * TO;
    const int y0 = (tile / NTX) * TO;
    const int z0 = zc * ZC;

    const int yl = tid >> 4, xl = tid & 15;
    const bool valid = (x0 + xl < MM) && (y0 + yl < MM);

    // loader mapping (tid < 144): 24 rows x 6 quads, one float4 per array
    const int lrow = tid / 6;
    const int lq   = tid - 6 * lrow;
    const int gy   = min(y0 + lrow, NN - 1);   // clamps only feed invalid outputs
    const int gx   = min(x0 + lq * 4, NN - 4);
    const size_t pbase = (size_t)gy * NN + gx;

    // X mapping (tid < 96): 96 items = (row, quarter); all 5 channels per thread
    const int rowX = tid >> 2;
    const int xbX  = (tid & 3) * 4;

    // Y mapping (tid 96..175): 80 items = (ch, x); full column per thread
    const int eY = tid - 96;
    const int cY = eY >> 4;
    const int xY = eY & 15;

    float4 pI, pJ;                             // prefetch registers
    if (tid < 144) {
        size_t a = (size_t)z0 * (NN * NN) + pbase;
        pI = *(const float4*)(I + a);
        pJ = *(const float4*)(J + a);
    }

    float ring[9][5];                          // z-window history (static idx only)
    float sz[5] = {0.f, 0.f, 0.f, 0.f, 0.f};
    float cc_acc = 0.f;

    for (int kb = 0; kb <= KMAX; kb += 9) {
#pragma unroll
        for (int ki = 0; ki < 9; ++ki) {
            const int k = kb + ki;             // pipeline step (block-uniform)
            if (k > KMAX) continue;

            // ============== Group 1: X(k-1) | Y(k-2), disjoint threads ==============
            if (k >= 1 && k <= PL && tid < 96) {
                // X: read 12-float I,J windows ONCE, produce 4 x-sums for all 5 ch
                const int b = (k - 1) & 1;
                const float4* Ir = (const float4*)&Pld[rowX * PSTR + xbX];
                const float4* Jr = (const float4*)&Pld[PCH + rowX * PSTR + xbX];
                float4 i0 = Ir[0], i1 = Ir[1], i2 = Ir[2];
                float4 j0 = Jr[0], j1 = Jr[1], j2 = Jr[2];
                float iv[12], jv[12];
                iv[0]=i0.x; iv[1]=i0.y; iv[2]=i0.z; iv[3]=i0.w;
                iv[4]=i1.x; iv[5]=i1.y; iv[6]=i1.z; iv[7]=i1.w;
                iv[8]=i2.x; iv[9]=i2.y; iv[10]=i2.z; iv[11]=i2.w;
                jv[0]=j0.x; jv[1]=j0.y; jv[2]=j0.z; jv[3]=j0.w;
                jv[4]=j1.x; jv[5]=j1.y; jv[6]=j1.z; jv[7]=j1.w;
                jv[8]=j2.x; jv[9]=j2.y; jv[10]=j2.z; jv[11]=j2.w;
#pragma unroll
                for (int c = 0; c < 5; ++c) {   // static unroll: selects fold away
                    float m[12];
#pragma unroll
                    for (int t = 0; t < 12; ++t) {
                        float av = (c & 1) ? jv[t] : iv[t];        // 0,2,4->I 1,3->J
                        float bv = (c < 2) ? 1.0f : ((c == 2) ? iv[t] : jv[t]);
                        m[t] = av * bv;
                    }
                    float s = m[0]+m[1]+m[2]+m[3]+m[4]+m[5]+m[6]+m[7]+m[8];
                    float* W = &xsb[b][c * XCH + rowX];
                    W[xbX * XROW] = s;
#pragma unroll
                    for (int t = 1; t < 4; ++t) {
                        s += m[t + 8] - m[t - 1];
                        W[(xbX + t) * XROW] = s;
                    }
                }
            }
            if (k >= 2 && k <= PL + 1 && tid >= 96 && tid < 176) {
                // Y: read full 24-row column (6 x b128), slide 16 y-outputs
                const int b = (k - 2) & 1;
                const float4* R = (const float4*)&xsb[b][cY * XCH + xY * XROW];
                float4 w0 = R[0], w1 = R[1], w2 = R[2], w3 = R[3], w4 = R[4], w5 = R[5];
                float m[24];
                m[0]=w0.x;  m[1]=w0.y;  m[2]=w0.z;  m[3]=w0.w;
                m[4]=w1.x;  m[5]=w1.y;  m[6]=w1.z;  m[7]=w1.w;
                m[8]=w2.x;  m[9]=w2.y;  m[10]=w2.z; m[11]=w2.w;
                m[12]=w3.x; m[13]=w3.y; m[14]=w3.z; m[15]=w3.w;
                m[16]=w4.x; m[17]=w4.y; m[18]=w4.z; m[19]=w4.w;
                m[20]=w5.x; m[21]=w5.y; m[22]=w5.z; m[23]=w5.w;
                float o[16];
                float s = m[0]+m[1]+m[2]+m[3]+m[4]+m[5]+m[6]+m[7]+m[8];
                o[0] = s;
#pragma unroll
                for (int t = 1; t < 16; ++t) {
                    s += m[t + 8] - m[t - 1];
                    o[t] = s;
                }
                float4* Wv = (float4*)&ysb[b][cY * YCH + xY * YROW];
                float4 oa = {o[0],  o[1],  o[2],  o[3]};
                float4 ob = {o[4],  o[5],  o[6],  o[7]};
                float4 oc = {o[8],  o[9],  o[10], o[11]};
                float4 od = {o[12], o[13], o[14], o[15]};
                Wv[0] = oa; Wv[1] = ob; Wv[2] = oc; Wv[3] = od;
            }
            __syncthreads();

            // ============== Group 2: commit(k)+prefetch(k+1) | Z(k-3) ==============
            if (k <= PL - 1 && tid < 144) {
                *(float4*)&Pld[lrow * PSTR + lq * 4]       = pI;
                *(float4*)&Pld[PCH + lrow * PSTR + lq * 4] = pJ;
                if (k <= PL - 2) {
                    size_t adr = (size_t)(z0 + k + 1) * (NN * NN) + pbase;
                    pI = *(const float4*)(I + adr);
                    pJ = *(const float4*)(J + adr);
                }
            }
            if (k >= 3) {
                // Z: per-column sliding z-window over ys[(k-3)&1] + cc
                const int b = (k - 3) & 1;
                const int slot  = (ki + 6) % 9;   // (k-3)%9, static per unrolled copy
                const int slot2 = (ki + 7) % 9;   // (k-3-8)%9
                float v[5];
#pragma unroll
                for (int c = 0; c < 5; ++c) {
                    v[c] = ysb[b][c * YCH + xl * YROW + yl];
                    sz[c] += v[c];
                    ring[slot][c] = v[c];
                }
                if (k >= 11) {                    // pz = k-3 >= 8: emit output
                    cc_acc += valid ? cc_of(sz) : 0.f;
#pragma unroll
                    for (int c = 0; c < 5; ++c) sz[c] -= ring[slot2][c];
                }
            }
            __syncthreads();
        }
    }

    // ---- block reduction (deterministic) ----
    for (int off = 32; off > 0; off >>= 1)
        cc_acc += __shfl_down(cc_acc, off, 64);
    if ((tid & 63) == 0) red[tid >> 6] = cc_acc;
    __syncthreads();
    if (tid == 0) partial[orig] = red[0] + red[1] + red[2] + red[3];
}

// ---- final deterministic reduction over 800 partials ----
__global__ __launch_bounds__(256) void lncc_final(
    const float* __restrict__ partial, float* __restrict__ out)
{
    double s = 0.0;
    for (int i = threadIdx.x; i < NBLK; i += 256)
        s += (double)partial[i];
    for (int off = 32; off > 0; off >>= 1)
        s += __shfl_down(s, off, 64);
    __shared__ double red[4];
    const int lane = threadIdx.x & 63, wid = threadIdx.x >> 6;
    if (lane == 0) red[wid] = s;
    __syncthreads();
    if (threadIdx.x == 0) {
        double tot = red[0] + red[1] + red[2] + red[3];
        out[0] = (float)(1.0 - tot / ((double)MM * MM * MM));
    }
}

extern "C" void kernel_launch(void* const* d_in, const int* in_sizes, int n_in,
                              void* d_out, int out_size, void* d_ws, size_t ws_size,
                              hipStream_t stream) {
    const float* I = (const float*)d_in[0];
    const float* J = (const float*)d_in[1];
    // d_in[2]: all-ones 9x9x9 filter, folded into the box-sum algebra.

    float* partial = (float*)d_ws;             // NBLK floats

    lncc_fused<<<NBLK, 256, 0, stream>>>(I, J, partial);
    lncc_final<<<1,    256, 0, stream>>>(partial, (float*)d_out);
    (void)in_sizes; (void)n_in; (void)out_size; (void)ws_size;
}